// Round 9
// baseline (442.794 us; speedup 1.0000x reference)
//
#include <hip/hip_runtime.h>
#include <math.h>

#define B_ 2
#define S_ 1024
#define E_ 1024
#define D_ 2048
#define H_ 8
#define KV_ 4
#define HD_ 256
#define WINDOW_ 512u
#define SCALE_ 0.0625f
#define CAP_ 50.0f
#define EPS_ 1e-6f
#define CROSS_OK (-7)
#define KINV (-2147483647 - 1)

typedef __bf16 bf8_t __attribute__((ext_vector_type(8)));
typedef float fx4 __attribute__((ext_vector_type(4)));
#define MFMA16(a, b, c) __builtin_amdgcn_mfma_f32_16x16x32_bf16((a), (b), (c), 0, 0, 0)

typedef __attribute__((address_space(1))) unsigned int gas_u32;
typedef __attribute__((address_space(3))) unsigned int las_u32;
__device__ __forceinline__ void gl2lds16(const void* g, void* l) {
    __builtin_amdgcn_global_load_lds((const gas_u32*)g, (las_u32*)l, 16, 0, 0);
}

union U4 { __bf16 b[4]; unsigned long long u; };

// p = exp(50*tanh(dot*SCALE/50) - 50) = exp(-100/(exp(dot*2*SCALE/50)+1))
__device__ __forceinline__ float pexp(float dot) {
    float e = __expf(dot * (2.0f * SCALE_ / CAP_));
    return __expf(-(2.0f * CAP_) / (e + 1.0f));
}

// =================== merged prep: tobf16 x2, tsplit x4, segscan ==============
__device__ __forceinline__ void dev_tobf16(const float* __restrict__ x,
                                           __bf16* __restrict__ y, int n4, int i) {
    if (i >= n4) return;
    float4 v = ((const float4*)x)[i];
    U4 p;
    p.b[0] = (__bf16)v.x; p.b[1] = (__bf16)v.y;
    p.b[2] = (__bf16)v.z; p.b[3] = (__bf16)v.w;
    *(unsigned long long*)&y[(size_t)i * 4] = p.u;
}

// 64x64 tile transpose+split: float4 loads, 8B packed bf16 stores (old version
// used scalar 2B stores -- store-side vectorization, Common-mistake #2).
__device__ __forceinline__ void dev_tsplit64(const float* __restrict__ W,
                                             __bf16* __restrict__ Th,
                                             __bf16* __restrict__ Tl, int K, int N,
                                             int bx, int by, int t,
                                             float (*tile)[68], int wlo) {
    const int q = t & 15, s = t >> 4;     // col/row quad index, 16-group
    const int k0 = bx * 64, n0 = by * 64;
#pragma unroll
    for (int rr = 0; rr < 4; ++rr) {
        int row = rr * 16 + s;
        *(float4*)&tile[row][q * 4] =
            *(const float4*)&W[(size_t)(k0 + row) * N + n0 + q * 4];
    }
    __syncthreads();
#pragma unroll
    for (int nn = 0; nn < 4; ++nn) {
        int n = nn * 16 + s;
        U4 ph, pl;
#pragma unroll
        for (int i = 0; i < 4; ++i) {
            float v = tile[q * 4 + i][n];
            __bf16 h = (__bf16)v;
            ph.b[i] = h;
            pl.b[i] = (__bf16)(v - (float)h);
        }
        size_t o = (size_t)(n0 + n) * K + k0 + q * 4;
        *(unsigned long long*)&Th[o] = ph.u;
        if (wlo) *(unsigned long long*)&Tl[o] = pl.u;
    }
}

__device__ __forceinline__ void dev_segscan(const int* __restrict__ pos,
                                            const int* __restrict__ dm,
                                            const int* __restrict__ em,
                                            int* __restrict__ seg,
                                            int* __restrict__ ki,
                                            int b, int t, int* wsum) {
    const int base = b * 1024 + t * 4;
    int4 p = *(const int4*)&pos[base];
    int pm1 = (t == 0) ? 0 : pos[base - 1];
    int r0 = (t == 0) ? 1 : (p.x <= pm1 ? 1 : 0);
    int r1 = (p.y <= p.x), r2 = (p.z <= p.y), r3 = (p.w <= p.z);
    int c0 = r0, c1 = c0 + r1, c2 = c1 + r2, c3 = c2 + r3;
    const int lane = t & 63, wv = t >> 6;
    int x = c3;
#pragma unroll
    for (int off = 1; off < 64; off <<= 1) {
        int y = __shfl_up(x, off, 64);
        if (lane >= off) x += y;
    }
    if (lane == 63) wsum[wv] = x;
    __syncthreads();
    int woff = 0;
#pragma unroll
    for (int w = 0; w < 4; ++w) if (w < wv) woff += wsum[w];
    const int excl = woff + x - c3;
    int sv[4] = {excl + c0, excl + c1, excl + c2, excl + c3};
    int4 dmv = *(const int4*)&dm[base];
    int4 emv = *(const int4*)&em[base];
    int dma[4] = {dmv.x, dmv.y, dmv.z, dmv.w};
    int ema[4] = {emv.x, emv.y, emv.z, emv.w};
#pragma unroll
    for (int r = 0; r < 4; ++r) {
        seg[base + r] = sv[r];
        ki[b * 2048 + t * 4 + r] = dma[r] ? sv[r] : KINV;
        ki[b * 2048 + 1024 + t * 4 + r] = ema[r] ? CROSS_OK : KINV;
    }
}

// grid = 4096(hs) + 4096(enc) + 1024(wq) + 512(wk) + 512(wv) + 1024(wo) + 2 = 11266
__global__ __launch_bounds__(256) void prep(
    const float* __restrict__ hs, const float* __restrict__ enc,
    const float* __restrict__ wq, const float* __restrict__ wk,
    const float* __restrict__ wvp, const float* __restrict__ wo,
    const int* __restrict__ pos, const int* __restrict__ dm,
    const int* __restrict__ em,
    __bf16* __restrict__ hs_bf, __bf16* __restrict__ enc_bf,
    __bf16* __restrict__ wqkvTH, __bf16* __restrict__ wqkvTL,
    __bf16* __restrict__ woTH, __bf16* __restrict__ woTL,
    int* __restrict__ seg, int* __restrict__ ki) {
    __shared__ float tile[64][68];
    __shared__ int wsum[4];
    int bid = blockIdx.x;
    const int t = threadIdx.x;
    if (bid < 4096) { dev_tobf16(hs, hs_bf, 1048576, bid * 256 + t); return; }
    bid -= 4096;
    if (bid < 4096) { dev_tobf16(enc, enc_bf, 1048576, bid * 256 + t); return; }
    bid -= 4096;
    if (bid < 1024) {
        dev_tsplit64(wq, wqkvTH, nullptr, 2048, 2048, bid & 31, bid >> 5, t, tile, 0);
        return;
    }
    bid -= 1024;
    if (bid < 512) {
        dev_tsplit64(wk, wqkvTH + (size_t)2048 * 2048, nullptr, 2048, 1024,
                     bid & 31, bid >> 5, t, tile, 0);
        return;
    }
    bid -= 512;
    if (bid < 512) {
        dev_tsplit64(wvp, wqkvTH + (size_t)3072 * 2048, wqkvTL + (size_t)3072 * 2048,
                     2048, 1024, bid & 31, bid >> 5, t, tile, 1);
        return;
    }
    bid -= 512;
    if (bid < 1024) {
        dev_tsplit64(wo, woTH, woTL, 2048, 2048, bid & 31, bid >> 5, t, tile, 1);
        return;
    }
    bid -= 1024;
    dev_segscan(pos, dm, em, seg, ki, bid, t, wsum);
}

// ---- GEMM core v2: 128x128 tile, BK=32, dbuf LDS + vmcnt(N) + XOR swizzle ---
// NPASS: 1 = Ah*Bh; 2 = +Ah*Bl; 3 = +Ah*Bl+Al*Bh.
// LDS slot map: slot(r,c) = r*4 + ((c + (r>>1)) & 3)  (16B chunks, c=0..3).
template <int NPASS>
__device__ __forceinline__ void gemm_core2(
    const __bf16* __restrict__ Ah, const __bf16* __restrict__ Al,
    const __bf16* __restrict__ Bh, const __bf16* __restrict__ Bl,
    int row0, int col0, int K,
    __bf16* As0, __bf16* As1, __bf16* Bs0, __bf16* Bs1, fx4 (&acc)[4][4]) {
    const int tid = threadIdx.x, lane = tid & 63, wv = tid >> 6;
    const int l15 = lane & 15, lq = lane >> 4;
    const int wm = (wv >> 1) * 64, wn = (wv & 1) * 64;
    constexpr int WCNT = (NPASS == 1) ? 0x0F74 : (NPASS == 2) ? 0x0F76 : 0x0F78;

    auto stage = [&](int buf, int k0) {
#pragma unroll
        for (int s = 0; s < 2; ++s) {
            int ch = (wv * 2 + s) * 64 + lane;        // physical slot 0..511
            int r = ch >> 2, cp = ch & 3;
            int cl = (cp - ((r >> 1) & 3)) & 3;       // logical k-chunk
            size_t ga = (size_t)(row0 + r) * K + k0 + cl * 8;
            size_t gb = (size_t)(col0 + r) * K + k0 + cl * 8;
            gl2lds16(Ah + ga, As0 + buf * 4096 + ch * 8);
            if (NPASS >= 3) gl2lds16(Al + ga, As1 + buf * 4096 + ch * 8);
            gl2lds16(Bh + gb, Bs0 + buf * 4096 + ch * 8);
            if (NPASS >= 2) gl2lds16(Bl + gb, Bs1 + buf * 4096 + ch * 8);
        }
    };

    stage(0, 0);
    for (int k0 = 0; k0 < K; k0 += 32) {
        const int buf = (k0 >> 5) & 1;
        const bool hasnext = (k0 + 32 < K);
        if (hasnext) stage(buf ^ 1, k0 + 32);
        if (hasnext) __builtin_amdgcn_s_waitcnt(WCNT);   // tile k0 landed; next in flight
        else         __builtin_amdgcn_s_waitcnt(0x0F70); // vmcnt(0)
        __builtin_amdgcn_s_barrier();
        __builtin_amdgcn_sched_barrier(0);

        const __bf16* A0 = As0 + buf * 4096;
        const __bf16* A1 = As1 + buf * 4096;
        const __bf16* B0 = Bs0 + buf * 4096;
        const __bf16* B1 = Bs1 + buf * 4096;
        bf8_t ah[4], al[4], bh[4], bl[4];
#pragma unroll
        for (int i = 0; i < 4; ++i) {
            int row = wm + i * 16 + l15;
            int sl = row * 4 + ((lq + (row >> 1)) & 3);
            ah[i] = *(const bf8_t*)(A0 + sl * 8);
            if (NPASS >= 3) al[i] = *(const bf8_t*)(A1 + sl * 8);
        }
#pragma unroll
        for (int j = 0; j < 4; ++j) {
            int row = wn + j * 16 + l15;
            int sl = row * 4 + ((lq + (row >> 1)) & 3);
            bh[j] = *(const bf8_t*)(B0 + sl * 8);
            if (NPASS >= 2) bl[j] = *(const bf8_t*)(B1 + sl * 8);
        }
#pragma unroll
        for (int i = 0; i < 4; ++i)
#pragma unroll
            for (int j = 0; j < 4; ++j) {
                acc[i][j] = MFMA16(ah[i], bh[j], acc[i][j]);
                if (NPASS >= 2) acc[i][j] = MFMA16(ah[i], bl[j], acc[i][j]);
                if (NPASS >= 3) acc[i][j] = MFMA16(al[i], bh[j], acc[i][j]);
            }
        __builtin_amdgcn_sched_barrier(0);
        __builtin_amdgcn_s_barrier();     // protect buf before re-stage next iter
    }
}

// ---- GEMM core half-N: 128x64 tile, 256 thr (4 waves = 2M x 2N), NPASS=3 ---
__device__ __forceinline__ void gemm_core_half(
    const __bf16* __restrict__ Ah, const __bf16* __restrict__ Al,
    const __bf16* __restrict__ Bh, const __bf16* __restrict__ Bl,
    int row0, int col0, int K,
    __bf16* As0, __bf16* As1, __bf16* Bs0, __bf16* Bs1, fx4 (&acc)[4][2]) {
    const int tid = threadIdx.x, lane = tid & 63, wv = tid >> 6;
    const int l15 = lane & 15, lq = lane >> 4;
    const int wm = (wv >> 1) * 64, wn = (wv & 1) * 32;

    auto stage = [&](int buf, int k0) {
#pragma unroll
        for (int s = 0; s < 2; ++s) {                 // A: 512 chunks, 2/thread
            int ch = s * 256 + tid;
            int r = ch >> 2, cp = ch & 3;
            int cl = (cp - ((r >> 1) & 3)) & 3;
            size_t ga = (size_t)(row0 + r) * K + k0 + cl * 8;
            gl2lds16(Ah + ga, As0 + buf * 4096 + ch * 8);
            gl2lds16(Al + ga, As1 + buf * 4096 + ch * 8);
        }
        {                                             // B: 256 chunks, 1/thread
            int ch = tid;
            int r = ch >> 2, cp = ch & 3;
            int cl = (cp - ((r >> 1) & 3)) & 3;
            size_t gb = (size_t)(col0 + r) * K + k0 + cl * 8;
            gl2lds16(Bh + gb, Bs0 + buf * 2048 + ch * 8);
            gl2lds16(Bl + gb, Bs1 + buf * 2048 + ch * 8);
        }
    };

    stage(0, 0);
    for (int k0 = 0; k0 < K; k0 += 32) {
        const int buf = (k0 >> 5) & 1;
        const bool hasnext = (k0 + 32 < K);
        if (hasnext) stage(buf ^ 1, k0 + 32);
        if (hasnext) __builtin_amdgcn_s_waitcnt(0x0F76);   // vmcnt(6)
        else         __builtin_amdgcn_s_waitcnt(0x0F70);   // vmcnt(0)
        __builtin_amdgcn_s_barrier();
        __builtin_amdgcn_sched_barrier(0);

        const __bf16* A0 = As0 + buf * 4096;
        const __bf16* A1 = As1 + buf * 4096;
        const __bf16* B0 = Bs0 + buf * 2048;
        const __bf16* B1 = Bs1 + buf * 2048;
        bf8_t ah[4], al[4], bh[2], bl[2];
#pragma unroll
        for (int i = 0; i < 4; ++i) {
            int row = wm + i * 16 + l15;
            int sl = row * 4 + ((lq + (row >> 1)) & 3);
            ah[i] = *(const bf8_t*)(A0 + sl * 8);
            al[i] = *(const bf8_t*)(A1 + sl * 8);
        }
#pragma unroll
        for (int j = 0; j < 2; ++j) {
            int row = wn + j * 16 + l15;
            int sl = row * 4 + ((lq + (row >> 1)) & 3);
            bh[j] = *(const bf8_t*)(B0 + sl * 8);
            bl[j] = *(const bf8_t*)(B1 + sl * 8);
        }
#pragma unroll
        for (int i = 0; i < 4; ++i)
#pragma unroll
            for (int j = 0; j < 2; ++j) {
                acc[i][j] = MFMA16(ah[i], bh[j], acc[i][j]);
                acc[i][j] = MFMA16(ah[i], bl[j], acc[i][j]);
                acc[i][j] = MFMA16(al[i], bh[j], acc[i][j]);
            }
        __builtin_amdgcn_sched_barrier(0);
        __builtin_amdgcn_s_barrier();
    }
}

// ---------------- fused projection GEMM (hs->q,k,v ; enc->kc,vc) ------------
__global__ __launch_bounds__(256) void gemm_proj(
    const __bf16* __restrict__ hsb, const __bf16* __restrict__ encb,
    const __bf16* __restrict__ BTh, const __bf16* __restrict__ BTl,
    float* __restrict__ qf32, float* __restrict__ ksf, float* __restrict__ kcf,
    __bf16* __restrict__ vtS, __bf16* __restrict__ vtC) {
    __shared__ __bf16 As0[8192], Bs0[8192], Bs1[8192];
    const int bx = blockIdx.x, row0 = blockIdx.y * 128;
    const __bf16* A;
    float* Ck; __bf16* Cv; int col0;
    if (bx < 32) { A = hsb;  col0 = bx * 128;               Ck = ksf; Cv = vtS; }
    else         { A = encb; col0 = (bx - 32) * 128 + 2048; Ck = kcf; Cv = vtC; }
    fx4 acc[4][4];
#pragma unroll
    for (int i = 0; i < 4; ++i)
#pragma unroll
        for (int j = 0; j < 4; ++j) acc[i][j] = (fx4){0.f, 0.f, 0.f, 0.f};
    if (col0 >= 3072)
        gemm_core2<2>(A, nullptr, BTh, BTl, row0, col0, D_, As0, nullptr, Bs0, Bs1, acc);
    else
        gemm_core2<1>(A, nullptr, BTh, BTl, row0, col0, D_, As0, nullptr, Bs0, Bs1, acc);

    const int tid = threadIdx.x, lane = tid & 63, wv = tid >> 6;
    const int l15 = lane & 15, lq = lane >> 4;
    const int wm = (wv >> 1) * 64, wn = (wv & 1) * 64;
    const int mode = (col0 < 2048) ? 0 : (col0 < 3072 ? 1 : 2);
#pragma unroll
    for (int i = 0; i < 4; ++i)
#pragma unroll
        for (int j = 0; j < 4; ++j) {
            int mb = row0 + wm + i * 16 + lq * 4;
            int n = col0 + wn + j * 16 + l15;
            if (mode == 0) {
#pragma unroll
                for (int r = 0; r < 4; ++r)
                    qf32[(size_t)(mb + r) * 2048 + n] = acc[i][j][r];
            } else if (mode == 1) {
                int nk = n - 2048;
#pragma unroll
                for (int r = 0; r < 4; ++r)
                    Ck[(size_t)(mb + r) * 1024 + nk] = acc[i][j][r];
            } else {
                int nv = n - 3072;
                int b = mb >> 10, s = mb & 1023;
                int kv = nv >> 8, d = nv & 255;
                U4 pk;
#pragma unroll
                for (int r = 0; r < 4; ++r) pk.b[r] = (__bf16)acc[i][j][r];
                *(unsigned long long*)&Cv[((size_t)(b * KV_ + kv) * HD_ + d) * 1024 + s] = pk.u;
            }
        }
}

// ---------------- output GEMM (3-term split), 128x64 tiles ------------------
__global__ __launch_bounds__(256) void gemm_out(
    const __bf16* __restrict__ Ah, const __bf16* __restrict__ Al,
    const __bf16* __restrict__ Bh, const __bf16* __restrict__ Bl,
    float* __restrict__ C) {
    __shared__ __bf16 As0[8192], As1[8192], Bs0[4096], Bs1[4096];
    const int row0 = blockIdx.y * 128, col0 = blockIdx.x * 64;
    fx4 acc[4][2];
#pragma unroll
    for (int i = 0; i < 4; ++i)
#pragma unroll
        for (int j = 0; j < 2; ++j) acc[i][j] = (fx4){0.f, 0.f, 0.f, 0.f};
    gemm_core_half(Ah, Al, Bh, Bl, row0, col0, 2048, As0, As1, Bs0, Bs1, acc);
    const int tid = threadIdx.x, lane = tid & 63, wv = tid >> 6;
    const int l15 = lane & 15, lq = lane >> 4;
    const int wm = (wv >> 1) * 64, wn = (wv & 1) * 32;
#pragma unroll
    for (int i = 0; i < 4; ++i)
#pragma unroll
        for (int j = 0; j < 2; ++j) {
            int mb = row0 + wm + i * 16 + lq * 4;
            int n = col0 + wn + j * 16 + l15;
#pragma unroll
            for (int r = 0; r < 4; ++r)
                C[(size_t)(mb + r) * 2048 + n] = acc[i][j][r];
        }
}

// -------- merged RMSNorm (+optional RoPE), wave-per-row, shuffle RoPE -------
__global__ __launch_bounds__(256) void rms_all(
    const float* __restrict__ qf32, const float* __restrict__ ksf,
    const float* __restrict__ kcf,
    __bf16* __restrict__ q_bf, __bf16* __restrict__ k_bf,
    __bf16* __restrict__ kc_bf,
    const float* __restrict__ qnw, const float* __restrict__ knw,
    const float* __restrict__ cs, const float* __restrict__ sn) {
    const int t = threadIdx.x, wvi = t >> 6, lane = t & 63;
    const int row = blockIdx.x * 4 + wvi;       // 0..32767, no group straddle
    const float* x; __bf16* out; const float* w;
    int nsh, do_rope, trans, rbase;
    if (row < 16384)      { rbase = row;         x = qf32; out = q_bf;  w = qnw; nsh = 3; do_rope = 1; trans = 0; }
    else if (row < 24576) { rbase = row - 16384; x = ksf;  out = k_bf;  w = knw; nsh = 2; do_rope = 1; trans = 1; }
    else                  { rbase = row - 24576; x = kcf;  out = kc_bf; w = knw; nsh = 2; do_rope = 0; trans = 1; }
    float4 v = ((const float4*)x)[(size_t)rbase * 64 + lane];
    float ss = v.x * v.x + v.y * v.y + v.z * v.z + v.w * v.w;
#pragma unroll
    for (int off = 32; off; off >>= 1) ss += __shfl_xor(ss, off, 64);
    float scale = rsqrtf(ss * (1.0f / HD_) + EPS_);
    float4 w4 = ((const float4*)w)[lane];
    float y0 = v.x * scale * (1.0f + w4.x);
    float y1 = v.y * scale * (1.0f + w4.y);
    float y2 = v.z * scale * (1.0f + w4.z);
    float y3 = v.w * scale * (1.0f + w4.w);
    const int m = rbase >> nsh;
    if (do_rope) {
        float r0 = __shfl_xor(y0, 32, 64);
        float r1 = __shfl_xor(y1, 32, 64);
        float r2 = __shfl_xor(y2, 32, 64);
        float r3 = __shfl_xor(y3, 32, 64);
        float sg = (lane < 32) ? -1.0f : 1.0f;
        float4 c4 = ((const float4*)cs)[(size_t)m * 64 + lane];
        float4 s4 = ((const float4*)sn)[(size_t)m * 64 + lane];
        y0 = y0 * c4.x + sg * r0 * s4.x;
        y1 = y1 * c4.y + sg * r1 * s4.y;
        y2 = y2 * c4.z + sg * r2 * s4.z;
        y3 = y3 * c4.w + sg * r3 * s4.w;
    }
    size_t oidx;
    if (trans) {
        int nh = 1 << nsh;
        int hh = rbase & (nh - 1);
        int b = m >> 10, s = m & 1023;
        oidx = ((size_t)(b * nh + hh) * 1024 + s) * HD_ + lane * 4;
    } else {
        oidx = (size_t)rbase * HD_ + lane * 4;
    }
    U4 pk;
    pk.b[0] = (__bf16)y0; pk.b[1] = (__bf16)y1;
    pk.b[2] = (__bf16)y2; pk.b[3] = (__bf16)y3;
    *(unsigned long long*)&out[oidx] = pk.u;
}

// ------- fused attention, balanced key-split, V UNSTAGED (L2-direct) --------
// r9: V-staging dropped (Common-mistake #7): per (b,kv) the V^T panel (512KB)
// is XCD-L2-resident (XCD-affine bid&7 mapping). PV reads V^T directly from
// global: lanes (l15, lq=0..3) cover 64B consecutive -> 16 full cachelines
// per instruction. Saves 4 gl2lds/thread/tile, halves vmcnt depth (8->4),
// frees 32KB LDS. K stays LDS-staged (read by both sc0/sc1 row groups).
__global__ __launch_bounds__(256, 1) void attn_part(
    const __bf16* __restrict__ qb,   // [B][S][H][256]
    const __bf16* __restrict__ kb,   // [B][KV][S][256]
    const __bf16* __restrict__ kcb,  // [B][KV][E][256]
    const __bf16* __restrict__ vtS,  // [B][KV][256][S]
    const __bf16* __restrict__ vtC,  // [B][KV][256][E]
    const int* __restrict__ seg, const int* __restrict__ ki,
    float* __restrict__ accS, float* __restrict__ accC,
    float* __restrict__ lsS, float* __restrict__ lsC) {
    __shared__ __bf16 Ks[2][8192];   // [key 0..31][dchunk 0..31 ^ (key&7)] x16B
    __shared__ __bf16 Ps[4][640];    // per-wave P, row stride 40
    __shared__ int kinfoS[1600];
    const int tid = threadIdx.x, lane = tid & 63, wv = tid >> 6;
    const int l15 = lane & 15, lq = lane >> 4;
    const int bid = blockIdx.x;
    const int role = bid >> 8;                 // 0 = self+crossLo, 1 = crossHi
    const int g = bid & 7;                     // XCD-affine: one (b,kv) per XCD
    const int b = g >> 2, kv = g & 3;
    const int idx = (bid >> 3) & 31;           // 0..31
    const int qt_raw = idx >> 1, h = kv * 2 + (idx & 1);
    const int qt = role ? (15 - qt_raw) : qt_raw;  // complementary CU pairing
    const int s0 = qt * 64;

    const int lo = (s0 >= 512) ? ((s0 - 511) & ~31) : 0;
    const int nts = (s0 + 64 - lo) >> 5;       // self tiles: 2..18
    const int ccr = (33 - nts) >> 1;           // blockA cross tiles: 7..15

    const __bf16* KbS = kb  + (size_t)(b * KV_ + kv) * (1024 * 256);
    const __bf16* VbS = vtS + (size_t)(b * KV_ + kv) * (256 * 1024);
    const __bf16* KbC = kcb + (size_t)(b * KV_ + kv) * (1024 * 256);
    const __bf16* VbC = vtC + (size_t)(b * KV_ + kv) * (256 * 1024);

    // stage kinfo slices: [0,nk0) self, [nk0, nk0+nk1) cross window
    if (role == 0) {
        const int nk0 = nts * 32, nk1 = ccr * 32;
        for (int i = tid; i < nk0; i += 256) kinfoS[i] = ki[b * 2048 + lo + i];
        for (int i = tid; i < nk1; i += 256)
            kinfoS[nk0 + i] = ki[b * 2048 + 1024 + i];
    } else {
        const int nk1 = (32 - ccr) * 32;
        for (int i = tid; i < nk1; i += 256)
            kinfoS[i] = ki[b * 2048 + 1024 + ccr * 32 + i];
    }
    __syncthreads();

    const int qpos = s0 + wv * 16 + l15;
    bf8_t qf[8];
    const __bf16* qrow = qb + ((size_t)(b * S_ + qpos) * H_ + h) * HD_;
#pragma unroll
    for (int f = 0; f < 8; ++f) qf[f] = *(const bf8_t*)(qrow + f * 32 + lq * 8);
    const int segq = seg[b * S_ + qpos];

    fx4 accO[16];
#pragma unroll
    for (int j = 0; j < 16; ++j) accO[j] = (fx4){0.f, 0.f, 0.f, 0.f};
    float lsum = 0.f;
    const int swzk = l15 & 7;

    // phase table: role0 = {self, crossLo}; role1 = {crossHi}
    const __bf16* phK[2]; const __bf16* phV[2];
    int phKey0[2], phKio[2], phNt[2], phSelf[2], nph;
    if (role == 0) {
        phK[0] = KbS; phV[0] = VbS; phKey0[0] = lo; phKio[0] = 0;
        phNt[0] = nts; phSelf[0] = 1;
        phK[1] = KbC; phV[1] = VbC; phKey0[1] = 0; phKio[1] = nts * 32;
        phNt[1] = ccr; phSelf[1] = 0;
        nph = 2;
    } else {
        phK[0] = KbC; phV[0] = VbC; phKey0[0] = ccr * 32; phKio[0] = 0;
        phNt[0] = 32 - ccr; phSelf[0] = 0;
        nph = 1;
    }

    for (int p = 0; p < nph; ++p) {
        const __bf16* Kb = phK[p];
        const __bf16* Vb = phV[p];
        const int key0 = phKey0[p], kiob = phKio[p], nt = phNt[p];
        const int selfm = phSelf[p];
        const int tgt = selfm ? segq : CROSS_OK;

        auto stage = [&](int buf, int t) {
            const __bf16* Kt = Kb + (size_t)(key0 + t * 32) * 256;
#pragma unroll
            for (int r = 0; r < 4; ++r) {
                int cid = r * 256 + tid;                     // 0..1023
                int key = cid >> 5, c = cid & 31;
                gl2lds16(Kt + key * 256 + (((c ^ (key & 7))) << 3), &Ks[buf][cid * 8]);
            }
        };

        stage(0, 0);
        for (int i = 0; i < nt; ++i) {
            const int kt0_c = key0 + i * 32;
            const int kio_c = kiob + i * 32;
            const bool hasnext = (i + 1 < nt);
            if (hasnext) stage((i + 1) & 1, i + 1);
            if (hasnext) __builtin_amdgcn_s_waitcnt(0x0F74);   // vmcnt(4)
            else         __builtin_amdgcn_s_waitcnt(0x0F70);   // vmcnt(0)
            __builtin_amdgcn_s_barrier();
            __builtin_amdgcn_sched_barrier(0);

            const __bf16* Ksb = Ks[i & 1];
            // QK^T: 4 independent 4-deep MFMA chains
            fx4 sc0a = (fx4){0.f, 0.f, 0.f, 0.f}, sc0b = (fx4){0.f, 0.f, 0.f, 0.f};
            fx4 sc1a = (fx4){0.f, 0.f, 0.f, 0.f}, sc1b = (fx4){0.f, 0.f, 0.f, 0.f};
            __builtin_amdgcn_s_setprio(1);
#pragma unroll
            for (int f = 0; f < 8; f += 2) {
                bf8_t k0a = *(const bf8_t*)&Ksb[(l15 * 32 + ((f * 4 + lq) ^ swzk)) * 8];
                bf8_t k1a = *(const bf8_t*)&Ksb[((16 + l15) * 32 + ((f * 4 + lq) ^ swzk)) * 8];
                bf8_t k0b = *(const bf8_t*)&Ksb[(l15 * 32 + (((f + 1) * 4 + lq) ^ swzk)) * 8];
                bf8_t k1b = *(const bf8_t*)&Ksb[((16 + l15) * 32 + (((f + 1) * 4 + lq) ^ swzk)) * 8];
                sc0a = MFMA16(k0a, qf[f], sc0a);
                sc1a = MFMA16(k1a, qf[f], sc1a);
                sc0b = MFMA16(k0b, qf[f + 1], sc0b);
                sc1b = MFMA16(k1b, qf[f + 1], sc1b);
            }
            __builtin_amdgcn_s_setprio(0);
            fx4 sc0 = sc0a + sc0b;
            fx4 sc1 = sc1a + sc1b;
            int4 ki0 = *(const int4*)&kinfoS[kio_c + lq * 4];
            int4 ki1 = *(const int4*)&kinfoS[kio_c + 16 + lq * 4];
            int ka0[4] = {ki0.x, ki0.y, ki0.z, ki0.w};
            int ka1[4] = {ki1.x, ki1.y, ki1.z, ki1.w};
            U4 p0, p1;
#pragma unroll
            for (int r = 0; r < 4; ++r) {
                int key0r = kt0_c + lq * 4 + r;
                float e0 = pexp(sc0[r]);
                float e1 = pexp(sc1[r]);
                bool ok0 = (ka0[r] == tgt) &&
                           (!selfm || (unsigned)(qpos - key0r) < WINDOW_);
                bool ok1 = (ka1[r] == tgt) &&
                           (!selfm || (unsigned)(qpos - key0r - 16) < WINDOW_);
                float v0 = ok0 ? e0 : 0.f;
                float v1 = ok1 ? e1 : 0.f;
                lsum += v0 + v1;
                p0.b[r] = (__bf16)v0;
                p1.b[r] = (__bf16)v1;
            }
            *(unsigned long long*)&Ps[wv][l15 * 40 + lq * 4] = p0.u;
            *(unsigned long long*)&Ps[wv][l15 * 40 + 16 + lq * 4] = p1.u;
            bf8_t pf = *(const bf8_t*)&Ps[wv][l15 * 40 + lq * 8];
            // PV: V^T direct from global (L2-resident, 64B-coalesced per
            // (l15,lq) group); addresses independent of softmax -> loads hoist
            const __bf16* Vtc = Vb + kt0_c + lq * 8;
            __builtin_amdgcn_s_setprio(1);
#pragma unroll
            for (int j = 0; j < 16; ++j) {
                bf8_t vb = *(const bf8_t*)(Vtc + (size_t)(j * 16 + l15) * 1024);
                accO[j] = MFMA16(pf, vb, accO[j]);
            }
            __builtin_amdgcn_s_setprio(0);
            __builtin_amdgcn_sched_barrier(0);
            __builtin_amdgcn_s_barrier();      // protect Ks before re-stage
        }
    }

    lsum += __shfl_xor(lsum, 16, 64);
    lsum += __shfl_xor(lsum, 32, 64);
    float* accT = role ? accC : accS;
    float* lsT  = role ? lsC  : lsS;
    if (lq == 0) lsT[(size_t)(b * S_ + qpos) * 8 + h] = lsum;
#pragma unroll
    for (int j = 0; j < 16; ++j)
#pragma unroll
        for (int r = 0; r < 4; ++r) {
            size_t idx2 = (size_t)(b * S_ + s0 + wv * 16 + lq * 4 + r) * 2048 +
                          h * 256 + j * 16 + l15;
            accT[idx2] = accO[j][r];
        }
}

// ---------------- combine partials -> normalized bf16 hi/lo -----------------
__global__ __launch_bounds__(256) void combine(
    const float* __restrict__ aS, const float* __restrict__ aC,
    const float* __restrict__ lS, const float* __restrict__ lC,
    __bf16* __restrict__ aH, __bf16* __restrict__ aL) {
    int i = blockIdx.x * 256 + threadIdx.x;      // group of 4 floats
    size_t base = (size_t)i * 4;
    int row = (int)(base >> 11);
    int h = (int)((base >> 8) & 7);
    float inv = 1.0f / (lS[row * 8 + h] + lC[row * 8 + h]);
    float4 a = ((const float4*)aS)[i];
    float4 c = ((const float4*)aC)[i];
    float o[4] = {(a.x + c.x) * inv, (a.y + c.y) * inv,
                  (a.z + c.z) * inv, (a.w + c.w) * inv};
    U4 ph, pl;
#pragma unroll
    for (int r = 0; r < 4; ++r) {
        __bf16 hi = (__bf16)o[r];
        ph.b[r] = hi;
        pl.b[r] = (__bf16)(o[r] - (float)hi);
    }
    *(unsigned long long*)&aH[base] = ph.u;
    *(unsigned long long*)&aL[base] = pl.u;
}

extern "C" void kernel_launch(void* const* d_in, const int* in_sizes, int n_in,
                              void* d_out, int out_size, void* d_ws, size_t ws_size,
                              hipStream_t stream) {
    (void)in_sizes; (void)n_in; (void)out_size; (void)ws_size;
    const float* hs  = (const float*)d_in[0];
    const float* enc = (const float*)d_in[1];
    const float* cs  = (const float*)d_in[2];
    const float* sn  = (const float*)d_in[3];
    const float* wq  = (const float*)d_in[4];
    const float* wk  = (const float*)d_in[5];
    const float* wv  = (const float*)d_in[6];
    const float* wo  = (const float*)d_in[7];
    const float* qnw = (const float*)d_in[8];
    const float* knw = (const float*)d_in[9];
    const int* dm    = (const int*)d_in[10];
    const int* em    = (const int*)d_in[11];
    const int* pos   = (const int*)d_in[12];
    float* out = (float*)d_out;

    char* ws = (char*)d_ws;
    const size_t MB = 1ull << 20;
    __bf16* hs_bf   = (__bf16*)(ws + 0 * MB);    // 8 MB   (dead after gemm_proj)
    __bf16* enc_bf  = (__bf16*)(ws + 8 * MB);    // 8 MB   (dead after gemm_proj)
    __bf16* wqkvTH  = (__bf16*)(ws + 16 * MB);   // 16 MB  (dead after gemm_proj)
    __bf16* wqkvTL  = (__bf16*)(ws + 32 * MB);   // 16 MB  (only v region written)
    __bf16* woTH    = (__bf16*)(ws + 48 * MB);   // 8 MB
    __bf16* woTL    = (__bf16*)(ws + 56 * MB);   // 8 MB
    float*  qf32    = (float*)(ws + 64 * MB);    // 16 MB  (dead after rms_all)
    float*  ksf     = (float*)(ws + 80 * MB);    // 8 MB   (dead after rms_all)
    float*  kcf     = (float*)(ws + 88 * MB);    // 8 MB   (dead after rms_all)
    __bf16* k_bf    = (__bf16*)(ws + 104 * MB);  // 4 MB   [B][KV][S][256]
    __bf16* kc_bf   = (__bf16*)(ws + 108 * MB);  // 4 MB
    __bf16* vtS     = (__bf16*)(ws + 112 * MB);  // 4 MB   [B][KV][256][S]
    __bf16* vtC     = (__bf16*)(ws + 116 * MB);  // 4 MB
    int*    seg     = (int*)(ws + 120 * MB);     // 8 KB
    int*    kinfo   = (int*)(ws + 121 * MB);     // 16 KB
    __bf16* q_bf    = (__bf16*)(ws + 124 * MB);  // 8 MB   [B][S][H][256]
    // reuse of dead regions:
    __bf16* aoutH   = (__bf16*)(ws + 0 * MB);    // 8.39 MB over hs_bf
    __bf16* aoutL   = (__bf16*)(ws + 9 * MB);    // 8.39 MB over enc_bf+wqkvTH head
    float*  accS    = (float*)(ws + 64 * MB);    // 16.78 MB over qf32 (+ksf head)
    float*  accC    = (float*)(ws + 81 * MB);    // 16.78 MB over ksf tail+kcf+gap
    float*  lsS     = (float*)(ws + 98 * MB);    // 64 KB
    float*  lsC     = (float*)(ws + 99 * MB);    // 64 KB

    // 1 launch: tobf16 x2 + tsplit64 x4 + segscan
    prep<<<11266, 256, 0, stream>>>(hs, enc, wq, wk, wv, wo, pos, dm, em,
                                    hs_bf, enc_bf, wqkvTH, wqkvTL, woTH, woTL,
                                    seg, kinfo);

    gemm_proj<<<dim3(48, 16), 256, 0, stream>>>(hs_bf, enc_bf, wqkvTH, wqkvTL,
                                                qf32, ksf, kcf, vtS, vtC);

    rms_all<<<8192, 256, 0, stream>>>(qf32, ksf, kcf, q_bf, k_bf, kc_bf,
                                      qnw, knw, cs, sn);

    attn_part<<<512, 256, 0, stream>>>(q_bf, k_bf, kc_bf, vtS, vtC, seg, kinfo,
                                       accS, accC, lsS, lsC);
    combine<<<4096, 256, 0, stream>>>(accS, accC, lsS, lsC, aoutH, aoutL);

    gemm_out<<<dim3(32, 16), 256, 0, stream>>>(aoutH, aoutL, woTH, woTL, out);
}

// Round 10
// 370.850 us; speedup vs baseline: 1.1940x; 1.1940x over previous
//
#include <hip/hip_runtime.h>
#include <math.h>

#define B_ 2
#define S_ 1024
#define E_ 1024
#define D_ 2048
#define H_ 8
#define KV_ 4
#define HD_ 256
#define WINDOW_ 512u
#define SCALE_ 0.0625f
#define CAP_ 50.0f
#define EPS_ 1e-6f
#define CROSS_OK (-7)
#define KINV (-2147483647 - 1)

typedef __bf16 bf8_t __attribute__((ext_vector_type(8)));
typedef float fx4 __attribute__((ext_vector_type(4)));
#define MFMA16(a, b, c) __builtin_amdgcn_mfma_f32_16x16x32_bf16((a), (b), (c), 0, 0, 0)

typedef __attribute__((address_space(1))) unsigned int gas_u32;
typedef __attribute__((address_space(3))) unsigned int las_u32;
__device__ __forceinline__ void gl2lds16(const void* g, void* l) {
    __builtin_amdgcn_global_load_lds((const gas_u32*)g, (las_u32*)l, 16, 0, 0);
}

union U4 { __bf16 b[4]; unsigned long long u; };

// p = exp(50*tanh(dot*SCALE/50) - 50) = exp(-100/(exp(dot*2*SCALE/50)+1))
__device__ __forceinline__ float pexp(float dot) {
    float e = __expf(dot * (2.0f * SCALE_ / CAP_));
    return __expf(-(2.0f * CAP_) / (e + 1.0f));
}

// =================== merged prep: tobf16 x2, tsplit64 x4, segscan ============
__device__ __forceinline__ void dev_tobf16(const float* __restrict__ x,
                                           __bf16* __restrict__ y, int n4, int i) {
    if (i >= n4) return;
    float4 v = ((const float4*)x)[i];
    U4 p;
    p.b[0] = (__bf16)v.x; p.b[1] = (__bf16)v.y;
    p.b[2] = (__bf16)v.z; p.b[3] = (__bf16)v.w;
    *(unsigned long long*)&y[(size_t)i * 4] = p.u;
}

// 64x64 tile transpose+split: float4 loads, 8B packed bf16 stores
__device__ __forceinline__ void dev_tsplit64(const float* __restrict__ W,
                                             __bf16* __restrict__ Th,
                                             __bf16* __restrict__ Tl, int K, int N,
                                             int bx, int by, int t,
                                             float (*tile)[68], int wlo) {
    const int q = t & 15, s = t >> 4;     // col/row quad index, 16-group
    const int k0 = bx * 64, n0 = by * 64;
#pragma unroll
    for (int rr = 0; rr < 4; ++rr) {
        int row = rr * 16 + s;
        *(float4*)&tile[row][q * 4] =
            *(const float4*)&W[(size_t)(k0 + row) * N + n0 + q * 4];
    }
    __syncthreads();
#pragma unroll
    for (int nn = 0; nn < 4; ++nn) {
        int n = nn * 16 + s;
        U4 ph, pl;
#pragma unroll
        for (int i = 0; i < 4; ++i) {
            float v = tile[q * 4 + i][n];
            __bf16 h = (__bf16)v;
            ph.b[i] = h;
            pl.b[i] = (__bf16)(v - (float)h);
        }
        size_t o = (size_t)(n0 + n) * K + k0 + q * 4;
        *(unsigned long long*)&Th[o] = ph.u;
        if (wlo) *(unsigned long long*)&Tl[o] = pl.u;
    }
}

__device__ __forceinline__ void dev_segscan(const int* __restrict__ pos,
                                            const int* __restrict__ dm,
                                            const int* __restrict__ em,
                                            int* __restrict__ seg,
                                            int* __restrict__ ki,
                                            int b, int t, int* wsum) {
    const int base = b * 1024 + t * 4;
    int4 p = *(const int4*)&pos[base];
    int pm1 = (t == 0) ? 0 : pos[base - 1];
    int r0 = (t == 0) ? 1 : (p.x <= pm1 ? 1 : 0);
    int r1 = (p.y <= p.x), r2 = (p.z <= p.y), r3 = (p.w <= p.z);
    int c0 = r0, c1 = c0 + r1, c2 = c1 + r2, c3 = c2 + r3;
    const int lane = t & 63, wv = t >> 6;
    int x = c3;
#pragma unroll
    for (int off = 1; off < 64; off <<= 1) {
        int y = __shfl_up(x, off, 64);
        if (lane >= off) x += y;
    }
    if (lane == 63) wsum[wv] = x;
    __syncthreads();
    int woff = 0;
#pragma unroll
    for (int w = 0; w < 4; ++w) if (w < wv) woff += wsum[w];
    const int excl = woff + x - c3;
    int sv[4] = {excl + c0, excl + c1, excl + c2, excl + c3};
    int4 dmv = *(const int4*)&dm[base];
    int4 emv = *(const int4*)&em[base];
    int dma[4] = {dmv.x, dmv.y, dmv.z, dmv.w};
    int ema[4] = {emv.x, emv.y, emv.z, emv.w};
#pragma unroll
    for (int r = 0; r < 4; ++r) {
        seg[base + r] = sv[r];
        ki[b * 2048 + t * 4 + r] = dma[r] ? sv[r] : KINV;
        ki[b * 2048 + 1024 + t * 4 + r] = ema[r] ? CROSS_OK : KINV;
    }
}

// grid = 4096(hs) + 4096(enc) + 1024(wq) + 512(wk) + 512(wv) + 1024(wo) + 2 = 11266
__global__ __launch_bounds__(256) void prep(
    const float* __restrict__ hs, const float* __restrict__ enc,
    const float* __restrict__ wq, const float* __restrict__ wk,
    const float* __restrict__ wvp, const float* __restrict__ wo,
    const int* __restrict__ pos, const int* __restrict__ dm,
    const int* __restrict__ em,
    __bf16* __restrict__ hs_bf, __bf16* __restrict__ enc_bf,
    __bf16* __restrict__ wqkvTH, __bf16* __restrict__ wqkvTL,
    __bf16* __restrict__ woTH, __bf16* __restrict__ woTL,
    int* __restrict__ seg, int* __restrict__ ki) {
    __shared__ float tile[64][68];
    __shared__ int wsum[4];
    int bid = blockIdx.x;
    const int t = threadIdx.x;
    if (bid < 4096) { dev_tobf16(hs, hs_bf, 1048576, bid * 256 + t); return; }
    bid -= 4096;
    if (bid < 4096) { dev_tobf16(enc, enc_bf, 1048576, bid * 256 + t); return; }
    bid -= 4096;
    if (bid < 1024) {
        dev_tsplit64(wq, wqkvTH, nullptr, 2048, 2048, bid & 31, bid >> 5, t, tile, 0);
        return;
    }
    bid -= 1024;
    if (bid < 512) {
        dev_tsplit64(wk, wqkvTH + (size_t)2048 * 2048, nullptr, 2048, 1024,
                     bid & 31, bid >> 5, t, tile, 0);
        return;
    }
    bid -= 512;
    if (bid < 512) {
        dev_tsplit64(wvp, wqkvTH + (size_t)3072 * 2048, wqkvTL + (size_t)3072 * 2048,
                     2048, 1024, bid & 31, bid >> 5, t, tile, 1);
        return;
    }
    bid -= 512;
    if (bid < 1024) {
        dev_tsplit64(wo, woTH, woTL, 2048, 2048, bid & 31, bid >> 5, t, tile, 1);
        return;
    }
    bid -= 1024;
    dev_segscan(pos, dm, em, seg, ki, bid, t, wsum);
}

// ---- GEMM core v2: 128x128 tile, BK=32, dbuf LDS + vmcnt(N) + XOR swizzle ---
// NPASS: 1 = Ah*Bh; 2 = +Ah*Bl; 3 = +Ah*Bl+Al*Bh.
// LDS slot map: slot(r,c) = r*4 + ((c + (r>>1)) & 3)  (16B chunks, c=0..3).
template <int NPASS>
__device__ __forceinline__ void gemm_core2(
    const __bf16* __restrict__ Ah, const __bf16* __restrict__ Al,
    const __bf16* __restrict__ Bh, const __bf16* __restrict__ Bl,
    int row0, int col0, int K,
    __bf16* As0, __bf16* As1, __bf16* Bs0, __bf16* Bs1, fx4 (&acc)[4][4]) {
    const int tid = threadIdx.x, lane = tid & 63, wv = tid >> 6;
    const int l15 = lane & 15, lq = lane >> 4;
    const int wm = (wv >> 1) * 64, wn = (wv & 1) * 64;
    constexpr int WCNT = (NPASS == 1) ? 0x0F74 : (NPASS == 2) ? 0x0F76 : 0x0F78;

    auto stage = [&](int buf, int k0) {
#pragma unroll
        for (int s = 0; s < 2; ++s) {
            int ch = (wv * 2 + s) * 64 + lane;        // physical slot 0..511
            int r = ch >> 2, cp = ch & 3;
            int cl = (cp - ((r >> 1) & 3)) & 3;       // logical k-chunk
            size_t ga = (size_t)(row0 + r) * K + k0 + cl * 8;
            size_t gb = (size_t)(col0 + r) * K + k0 + cl * 8;
            gl2lds16(Ah + ga, As0 + buf * 4096 + ch * 8);
            if (NPASS >= 3) gl2lds16(Al + ga, As1 + buf * 4096 + ch * 8);
            gl2lds16(Bh + gb, Bs0 + buf * 4096 + ch * 8);
            if (NPASS >= 2) gl2lds16(Bl + gb, Bs1 + buf * 4096 + ch * 8);
        }
    };

    stage(0, 0);
    for (int k0 = 0; k0 < K; k0 += 32) {
        const int buf = (k0 >> 5) & 1;
        const bool hasnext = (k0 + 32 < K);
        if (hasnext) stage(buf ^ 1, k0 + 32);
        if (hasnext) __builtin_amdgcn_s_waitcnt(WCNT);   // tile k0 landed; next in flight
        else         __builtin_amdgcn_s_waitcnt(0x0F70); // vmcnt(0)
        __builtin_amdgcn_s_barrier();
        __builtin_amdgcn_sched_barrier(0);

        const __bf16* A0 = As0 + buf * 4096;
        const __bf16* A1 = As1 + buf * 4096;
        const __bf16* B0 = Bs0 + buf * 4096;
        const __bf16* B1 = Bs1 + buf * 4096;
        bf8_t ah[4], al[4], bh[4], bl[4];
#pragma unroll
        for (int i = 0; i < 4; ++i) {
            int row = wm + i * 16 + l15;
            int sl = row * 4 + ((lq + (row >> 1)) & 3);
            ah[i] = *(const bf8_t*)(A0 + sl * 8);
            if (NPASS >= 3) al[i] = *(const bf8_t*)(A1 + sl * 8);
        }
#pragma unroll
        for (int j = 0; j < 4; ++j) {
            int row = wn + j * 16 + l15;
            int sl = row * 4 + ((lq + (row >> 1)) & 3);
            bh[j] = *(const bf8_t*)(B0 + sl * 8);
            if (NPASS >= 2) bl[j] = *(const bf8_t*)(B1 + sl * 8);
        }
#pragma unroll
        for (int i = 0; i < 4; ++i)
#pragma unroll
            for (int j = 0; j < 4; ++j) {
                acc[i][j] = MFMA16(ah[i], bh[j], acc[i][j]);
                if (NPASS >= 2) acc[i][j] = MFMA16(ah[i], bl[j], acc[i][j]);
                if (NPASS >= 3) acc[i][j] = MFMA16(al[i], bh[j], acc[i][j]);
            }
        __builtin_amdgcn_sched_barrier(0);
        __builtin_amdgcn_s_barrier();     // protect buf before re-stage next iter
    }
}

// ---- GEMM core half-N: 128x64 tile, 256 thr (4 waves = 2M x 2N), NPASS=3 ---
__device__ __forceinline__ void gemm_core_half(
    const __bf16* __restrict__ Ah, const __bf16* __restrict__ Al,
    const __bf16* __restrict__ Bh, const __bf16* __restrict__ Bl,
    int row0, int col0, int K,
    __bf16* As0, __bf16* As1, __bf16* Bs0, __bf16* Bs1, fx4 (&acc)[4][2]) {
    const int tid = threadIdx.x, lane = tid & 63, wv = tid >> 6;
    const int l15 = lane & 15, lq = lane >> 4;
    const int wm = (wv >> 1) * 64, wn = (wv & 1) * 32;

    auto stage = [&](int buf, int k0) {
#pragma unroll
        for (int s = 0; s < 2; ++s) {                 // A: 512 chunks, 2/thread
            int ch = s * 256 + tid;
            int r = ch >> 2, cp = ch & 3;
            int cl = (cp - ((r >> 1) & 3)) & 3;
            size_t ga = (size_t)(row0 + r) * K + k0 + cl * 8;
            gl2lds16(Ah + ga, As0 + buf * 4096 + ch * 8);
            gl2lds16(Al + ga, As1 + buf * 4096 + ch * 8);
        }
        {                                             // B: 256 chunks, 1/thread
            int ch = tid;
            int r = ch >> 2, cp = ch & 3;
            int cl = (cp - ((r >> 1) & 3)) & 3;
            size_t gb = (size_t)(col0 + r) * K + k0 + cl * 8;
            gl2lds16(Bh + gb, Bs0 + buf * 2048 + ch * 8);
            gl2lds16(Bl + gb, Bs1 + buf * 2048 + ch * 8);
        }
    };

    stage(0, 0);
    for (int k0 = 0; k0 < K; k0 += 32) {
        const int buf = (k0 >> 5) & 1;
        const bool hasnext = (k0 + 32 < K);
        if (hasnext) stage(buf ^ 1, k0 + 32);
        if (hasnext) __builtin_amdgcn_s_waitcnt(0x0F76);   // vmcnt(6)
        else         __builtin_amdgcn_s_waitcnt(0x0F70);   // vmcnt(0)
        __builtin_amdgcn_s_barrier();
        __builtin_amdgcn_sched_barrier(0);

        const __bf16* A0 = As0 + buf * 4096;
        const __bf16* A1 = As1 + buf * 4096;
        const __bf16* B0 = Bs0 + buf * 2048;
        const __bf16* B1 = Bs1 + buf * 2048;
        bf8_t ah[4], al[4], bh[2], bl[2];
#pragma unroll
        for (int i = 0; i < 4; ++i) {
            int row = wm + i * 16 + l15;
            int sl = row * 4 + ((lq + (row >> 1)) & 3);
            ah[i] = *(const bf8_t*)(A0 + sl * 8);
            al[i] = *(const bf8_t*)(A1 + sl * 8);
        }
#pragma unroll
        for (int j = 0; j < 2; ++j) {
            int row = wn + j * 16 + l15;
            int sl = row * 4 + ((lq + (row >> 1)) & 3);
            bh[j] = *(const bf8_t*)(B0 + sl * 8);
            bl[j] = *(const bf8_t*)(B1 + sl * 8);
        }
#pragma unroll
        for (int i = 0; i < 4; ++i)
#pragma unroll
            for (int j = 0; j < 2; ++j) {
                acc[i][j] = MFMA16(ah[i], bh[j], acc[i][j]);
                acc[i][j] = MFMA16(ah[i], bl[j], acc[i][j]);
                acc[i][j] = MFMA16(al[i], bh[j], acc[i][j]);
            }
        __builtin_amdgcn_sched_barrier(0);
        __builtin_amdgcn_s_barrier();
    }
}

// ---------------- fused projection GEMM (hs->q,k,v ; enc->kc,vc) ------------
__global__ __launch_bounds__(256) void gemm_proj(
    const __bf16* __restrict__ hsb, const __bf16* __restrict__ encb,
    const __bf16* __restrict__ BTh, const __bf16* __restrict__ BTl,
    float* __restrict__ qf32, float* __restrict__ ksf, float* __restrict__ kcf,
    __bf16* __restrict__ vtS, __bf16* __restrict__ vtC) {
    __shared__ __bf16 As0[8192], Bs0[8192], Bs1[8192];
    const int bx = blockIdx.x, row0 = blockIdx.y * 128;
    const __bf16* A;
    float* Ck; __bf16* Cv; int col0;
    if (bx < 32) { A = hsb;  col0 = bx * 128;               Ck = ksf; Cv = vtS; }
    else         { A = encb; col0 = (bx - 32) * 128 + 2048; Ck = kcf; Cv = vtC; }
    fx4 acc[4][4];
#pragma unroll
    for (int i = 0; i < 4; ++i)
#pragma unroll
        for (int j = 0; j < 4; ++j) acc[i][j] = (fx4){0.f, 0.f, 0.f, 0.f};
    if (col0 >= 3072)
        gemm_core2<2>(A, nullptr, BTh, BTl, row0, col0, D_, As0, nullptr, Bs0, Bs1, acc);
    else
        gemm_core2<1>(A, nullptr, BTh, BTl, row0, col0, D_, As0, nullptr, Bs0, Bs1, acc);

    const int tid = threadIdx.x, lane = tid & 63, wv = tid >> 6;
    const int l15 = lane & 15, lq = lane >> 4;
    const int wm = (wv >> 1) * 64, wn = (wv & 1) * 64;
    const int mode = (col0 < 2048) ? 0 : (col0 < 3072 ? 1 : 2);
#pragma unroll
    for (int i = 0; i < 4; ++i)
#pragma unroll
        for (int j = 0; j < 4; ++j) {
            int mb = row0 + wm + i * 16 + lq * 4;
            int n = col0 + wn + j * 16 + l15;
            if (mode == 0) {
#pragma unroll
                for (int r = 0; r < 4; ++r)
                    qf32[(size_t)(mb + r) * 2048 + n] = acc[i][j][r];
            } else if (mode == 1) {
                int nk = n - 2048;
#pragma unroll
                for (int r = 0; r < 4; ++r)
                    Ck[(size_t)(mb + r) * 1024 + nk] = acc[i][j][r];
            } else {
                int nv = n - 3072;
                int b = mb >> 10, s = mb & 1023;
                int kv = nv >> 8, d = nv & 255;
                U4 pk;
#pragma unroll
                for (int r = 0; r < 4; ++r) pk.b[r] = (__bf16)acc[i][j][r];
                *(unsigned long long*)&Cv[((size_t)(b * KV_ + kv) * HD_ + d) * 1024 + s] = pk.u;
            }
        }
}

// ---------------- output GEMM (3-term split), 128x64 tiles ------------------
__global__ __launch_bounds__(256) void gemm_out(
    const __bf16* __restrict__ Ah, const __bf16* __restrict__ Al,
    const __bf16* __restrict__ Bh, const __bf16* __restrict__ Bl,
    float* __restrict__ C) {
    __shared__ __bf16 As0[8192], As1[8192], Bs0[4096], Bs1[4096];
    const int row0 = blockIdx.y * 128, col0 = blockIdx.x * 64;
    fx4 acc[4][2];
#pragma unroll
    for (int i = 0; i < 4; ++i)
#pragma unroll
        for (int j = 0; j < 2; ++j) acc[i][j] = (fx4){0.f, 0.f, 0.f, 0.f};
    gemm_core_half(Ah, Al, Bh, Bl, row0, col0, 2048, As0, As1, Bs0, Bs1, acc);
    const int tid = threadIdx.x, lane = tid & 63, wv = tid >> 6;
    const int l15 = lane & 15, lq = lane >> 4;
    const int wm = (wv >> 1) * 64, wn = (wv & 1) * 32;
#pragma unroll
    for (int i = 0; i < 4; ++i)
#pragma unroll
        for (int j = 0; j < 2; ++j) {
            int mb = row0 + wm + i * 16 + lq * 4;
            int n = col0 + wn + j * 16 + l15;
#pragma unroll
            for (int r = 0; r < 4; ++r)
                C[(size_t)(mb + r) * 2048 + n] = acc[i][j][r];
        }
}

// -------- merged RMSNorm (+optional RoPE), wave-per-row, shuffle RoPE -------
__global__ __launch_bounds__(256) void rms_all(
    const float* __restrict__ qf32, const float* __restrict__ ksf,
    const float* __restrict__ kcf,
    __bf16* __restrict__ q_bf, __bf16* __restrict__ k_bf,
    __bf16* __restrict__ kc_bf,
    const float* __restrict__ qnw, const float* __restrict__ knw,
    const float* __restrict__ cs, const float* __restrict__ sn) {
    const int t = threadIdx.x, wvi = t >> 6, lane = t & 63;
    const int row = blockIdx.x * 4 + wvi;       // 0..32767, no group straddle
    const float* x; __bf16* out; const float* w;
    int nsh, do_rope, trans, rbase;
    if (row < 16384)      { rbase = row;         x = qf32; out = q_bf;  w = qnw; nsh = 3; do_rope = 1; trans = 0; }
    else if (row < 24576) { rbase = row - 16384; x = ksf;  out = k_bf;  w = knw; nsh = 2; do_rope = 1; trans = 1; }
    else                  { rbase = row - 24576; x = kcf;  out = kc_bf; w = knw; nsh = 2; do_rope = 0; trans = 1; }
    float4 v = ((const float4*)x)[(size_t)rbase * 64 + lane];
    float ss = v.x * v.x + v.y * v.y + v.z * v.z + v.w * v.w;
#pragma unroll
    for (int off = 32; off; off >>= 1) ss += __shfl_xor(ss, off, 64);
    float scale = rsqrtf(ss * (1.0f / HD_) + EPS_);
    float4 w4 = ((const float4*)w)[lane];
    float y0 = v.x * scale * (1.0f + w4.x);
    float y1 = v.y * scale * (1.0f + w4.y);
    float y2 = v.z * scale * (1.0f + w4.z);
    float y3 = v.w * scale * (1.0f + w4.w);
    const int m = rbase >> nsh;
    if (do_rope) {
        float r0 = __shfl_xor(y0, 32, 64);
        float r1 = __shfl_xor(y1, 32, 64);
        float r2 = __shfl_xor(y2, 32, 64);
        float r3 = __shfl_xor(y3, 32, 64);
        float sg = (lane < 32) ? -1.0f : 1.0f;
        float4 c4 = ((const float4*)cs)[(size_t)m * 64 + lane];
        float4 s4 = ((const float4*)sn)[(size_t)m * 64 + lane];
        y0 = y0 * c4.x + sg * r0 * s4.x;
        y1 = y1 * c4.y + sg * r1 * s4.y;
        y2 = y2 * c4.z + sg * r2 * s4.z;
        y3 = y3 * c4.w + sg * r3 * s4.w;
    }
    size_t oidx;
    if (trans) {
        int nh = 1 << nsh;
        int hh = rbase & (nh - 1);
        int b = m >> 10, s = m & 1023;
        oidx = ((size_t)(b * nh + hh) * 1024 + s) * HD_ + lane * 4;
    } else {
        oidx = (size_t)rbase * HD_ + lane * 4;
    }
    U4 pk;
    pk.b[0] = (__bf16)y0; pk.b[1] = (__bf16)y1;
    pk.b[2] = (__bf16)y2; pk.b[3] = (__bf16)y3;
    *(unsigned long long*)&out[oidx] = pk.u;
}

// ------- fused attention, balanced key-split (r8 structure, V RE-STAGED) ----
// r10: revert r9's V-unstage -- direct-global PV loads shared the vmcnt FIFO
// with the K prefetch and exposed L2 latency on the MFMA path (63->137us).
// LDS gl2lds staging isolates compute from VMEM latency; keep it.
__global__ __launch_bounds__(256, 1) void attn_part(
    const __bf16* __restrict__ qb,   // [B][S][H][256]
    const __bf16* __restrict__ kb,   // [B][KV][S][256]
    const __bf16* __restrict__ kcb,  // [B][KV][E][256]
    const __bf16* __restrict__ vtS,  // [B][KV][256][S]
    const __bf16* __restrict__ vtC,  // [B][KV][256][E]
    const int* __restrict__ seg, const int* __restrict__ ki,
    float* __restrict__ accS, float* __restrict__ accC,
    float* __restrict__ lsS, float* __restrict__ lsC) {
    __shared__ __bf16 Ks[2][8192];   // [key 0..31][dchunk 0..31 ^ (key&7)] x16B
    __shared__ __bf16 Vs[2][8192];   // [d 0..255][kc 0..3 ^ ((d>>1)&3)] x16B
    __shared__ __bf16 Ps[4][640];    // per-wave P, row stride 40
    __shared__ int kinfoS[1600];
    const int tid = threadIdx.x, lane = tid & 63, wv = tid >> 6;
    const int l15 = lane & 15, lq = lane >> 4;
    const int bid = blockIdx.x;
    const int role = bid >> 8;                 // 0 = self+crossLo, 1 = crossHi
    const int g = bid & 7;                     // XCD-affine: one (b,kv) per XCD
    const int b = g >> 2, kv = g & 3;
    const int idx = (bid >> 3) & 31;           // 0..31
    const int qt_raw = idx >> 1, h = kv * 2 + (idx & 1);
    const int qt = role ? (15 - qt_raw) : qt_raw;  // complementary CU pairing
    const int s0 = qt * 64;

    const int lo = (s0 >= 512) ? ((s0 - 511) & ~31) : 0;
    const int nts = (s0 + 64 - lo) >> 5;       // self tiles: 2..18
    const int ccr = (33 - nts) >> 1;           // blockA cross tiles: 7..15

    const __bf16* KbS = kb  + (size_t)(b * KV_ + kv) * (1024 * 256);
    const __bf16* VbS = vtS + (size_t)(b * KV_ + kv) * (256 * 1024);
    const __bf16* KbC = kcb + (size_t)(b * KV_ + kv) * (1024 * 256);
    const __bf16* VbC = vtC + (size_t)(b * KV_ + kv) * (256 * 1024);

    // stage kinfo slices: [0,nk0) self, [nk0, nk0+nk1) cross window
    if (role == 0) {
        const int nk0 = nts * 32, nk1 = ccr * 32;
        for (int i = tid; i < nk0; i += 256) kinfoS[i] = ki[b * 2048 + lo + i];
        for (int i = tid; i < nk1; i += 256)
            kinfoS[nk0 + i] = ki[b * 2048 + 1024 + i];
    } else {
        const int nk1 = (32 - ccr) * 32;
        for (int i = tid; i < nk1; i += 256)
            kinfoS[i] = ki[b * 2048 + 1024 + ccr * 32 + i];
    }
    __syncthreads();

    const int qpos = s0 + wv * 16 + l15;
    bf8_t qf[8];
    const __bf16* qrow = qb + ((size_t)(b * S_ + qpos) * H_ + h) * HD_;
#pragma unroll
    for (int f = 0; f < 8; ++f) qf[f] = *(const bf8_t*)(qrow + f * 32 + lq * 8);
    const int segq = seg[b * S_ + qpos];

    fx4 accO[16];
#pragma unroll
    for (int j = 0; j < 16; ++j) accO[j] = (fx4){0.f, 0.f, 0.f, 0.f};
    float lsum = 0.f;
    const int swzk = l15 & 7;
    const int swzv = lq ^ ((l15 >> 1) & 3);

    // phase table: role0 = {self, crossLo}; role1 = {crossHi}
    const __bf16* phK[2]; const __bf16* phV[2];
    int phKey0[2], phKio[2], phNt[2], phSelf[2], nph;
    if (role == 0) {
        phK[0] = KbS; phV[0] = VbS; phKey0[0] = lo; phKio[0] = 0;
        phNt[0] = nts; phSelf[0] = 1;
        phK[1] = KbC; phV[1] = VbC; phKey0[1] = 0; phKio[1] = nts * 32;
        phNt[1] = ccr; phSelf[1] = 0;
        nph = 2;
    } else {
        phK[0] = KbC; phV[0] = VbC; phKey0[0] = ccr * 32; phKio[0] = 0;
        phNt[0] = 32 - ccr; phSelf[0] = 0;
        nph = 1;
    }

    for (int p = 0; p < nph; ++p) {
        const __bf16* Kb = phK[p];
        const __bf16* Vb = phV[p];
        const int key0 = phKey0[p], kiob = phKio[p], nt = phNt[p];
        const int selfm = phSelf[p];
        const int tgt = selfm ? segq : CROSS_OK;

        auto stage = [&](int buf, int t) {
            const __bf16* Kt = Kb + (size_t)(key0 + t * 32) * 256;
            const __bf16* Vt = Vb + (key0 + t * 32);
#pragma unroll
            for (int r = 0; r < 4; ++r) {
                int cid = r * 256 + tid;                     // 0..1023
                int key = cid >> 5, c = cid & 31;
                gl2lds16(Kt + key * 256 + (((c ^ (key & 7))) << 3), &Ks[buf][cid * 8]);
            }
#pragma unroll
            for (int r = 0; r < 4; ++r) {
                int cid = r * 256 + tid;
                int d = cid >> 2, kc = cid & 3;
                gl2lds16(Vt + (size_t)d * 1024 + ((kc ^ ((d >> 1) & 3)) << 3),
                         &Vs[buf][cid * 8]);
            }
        };

        stage(0, 0);
        for (int i = 0; i < nt; ++i) {
            const int kt0_c = key0 + i * 32;
            const int kio_c = kiob + i * 32;
            const bool hasnext = (i + 1 < nt);
            if (hasnext) stage((i + 1) & 1, i + 1);
            if (hasnext) __builtin_amdgcn_s_waitcnt(0x0F78);   // vmcnt(8)
            else         __builtin_amdgcn_s_waitcnt(0x0F70);   // vmcnt(0)
            __builtin_amdgcn_s_barrier();
            __builtin_amdgcn_sched_barrier(0);

            const __bf16* Ksb = Ks[i & 1];
            const __bf16* Vsb = Vs[i & 1];
            // QK^T: 4 independent 4-deep MFMA chains
            fx4 sc0a = (fx4){0.f, 0.f, 0.f, 0.f}, sc0b = (fx4){0.f, 0.f, 0.f, 0.f};
            fx4 sc1a = (fx4){0.f, 0.f, 0.f, 0.f}, sc1b = (fx4){0.f, 0.f, 0.f, 0.f};
            __builtin_amdgcn_s_setprio(1);
#pragma unroll
            for (int f = 0; f < 8; f += 2) {
                bf8_t k0a = *(const bf8_t*)&Ksb[(l15 * 32 + ((f * 4 + lq) ^ swzk)) * 8];
                bf8_t k1a = *(const bf8_t*)&Ksb[((16 + l15) * 32 + ((f * 4 + lq) ^ swzk)) * 8];
                bf8_t k0b = *(const bf8_t*)&Ksb[(l15 * 32 + (((f + 1) * 4 + lq) ^ swzk)) * 8];
                bf8_t k1b = *(const bf8_t*)&Ksb[((16 + l15) * 32 + (((f + 1) * 4 + lq) ^ swzk)) * 8];
                sc0a = MFMA16(k0a, qf[f], sc0a);
                sc1a = MFMA16(k1a, qf[f], sc1a);
                sc0b = MFMA16(k0b, qf[f + 1], sc0b);
                sc1b = MFMA16(k1b, qf[f + 1], sc1b);
            }
            __builtin_amdgcn_s_setprio(0);
            fx4 sc0 = sc0a + sc0b;
            fx4 sc1 = sc1a + sc1b;
            int4 ki0 = *(const int4*)&kinfoS[kio_c + lq * 4];
            int4 ki1 = *(const int4*)&kinfoS[kio_c + 16 + lq * 4];
            int ka0[4] = {ki0.x, ki0.y, ki0.z, ki0.w};
            int ka1[4] = {ki1.x, ki1.y, ki1.z, ki1.w};
            U4 p0, p1;
#pragma unroll
            for (int r = 0; r < 4; ++r) {
                int key0r = kt0_c + lq * 4 + r;
                float e0 = pexp(sc0[r]);
                float e1 = pexp(sc1[r]);
                bool ok0 = (ka0[r] == tgt) &&
                           (!selfm || (unsigned)(qpos - key0r) < WINDOW_);
                bool ok1 = (ka1[r] == tgt) &&
                           (!selfm || (unsigned)(qpos - key0r - 16) < WINDOW_);
                float v0 = ok0 ? e0 : 0.f;
                float v1 = ok1 ? e1 : 0.f;
                lsum += v0 + v1;
                p0.b[r] = (__bf16)v0;
                p1.b[r] = (__bf16)v1;
            }
            *(unsigned long long*)&Ps[wv][l15 * 40 + lq * 4] = p0.u;
            *(unsigned long long*)&Ps[wv][l15 * 40 + 16 + lq * 4] = p1.u;
            bf8_t pf = *(const bf8_t*)&Ps[wv][l15 * 40 + lq * 8];
            __builtin_amdgcn_s_setprio(1);
#pragma unroll
            for (int j = 0; j < 16; ++j) {
                bf8_t vb = *(const bf8_t*)&Vsb[((j * 16 + l15) * 4 + swzv) * 8];
                accO[j] = MFMA16(pf, vb, accO[j]);
            }
            __builtin_amdgcn_s_setprio(0);
            __builtin_amdgcn_sched_barrier(0);
            __builtin_amdgcn_s_barrier();      // protect buffers before re-stage
        }
    }

    lsum += __shfl_xor(lsum, 16, 64);
    lsum += __shfl_xor(lsum, 32, 64);
    float* accT = role ? accC : accS;
    float* lsT  = role ? lsC  : lsS;
    if (lq == 0) lsT[(size_t)(b * S_ + qpos) * 8 + h] = lsum;
#pragma unroll
    for (int j = 0; j < 16; ++j)
#pragma unroll
        for (int r = 0; r < 4; ++r) {
            size_t idx2 = (size_t)(b * S_ + s0 + wv * 16 + lq * 4 + r) * 2048 +
                          h * 256 + j * 16 + l15;
            accT[idx2] = accO[j][r];
        }
}

// ---------------- combine partials -> normalized bf16 hi/lo -----------------
__global__ __launch_bounds__(256) void combine(
    const float* __restrict__ aS, const float* __restrict__ aC,
    const float* __restrict__ lS, const float* __restrict__ lC,
    __bf16* __restrict__ aH, __bf16* __restrict__ aL) {
    int i = blockIdx.x * 256 + threadIdx.x;      // group of 4 floats
    size_t base = (size_t)i * 4;
    int row = (int)(base >> 11);
    int h = (int)((base >> 8) & 7);
    float inv = 1.0f / (lS[row * 8 + h] + lC[row * 8 + h]);
    float4 a = ((const float4*)aS)[i];
    float4 c = ((const float4*)aC)[i];
    float o[4] = {(a.x + c.x) * inv, (a.y + c.y) * inv,
                  (a.z + c.z) * inv, (a.w + c.w) * inv};
    U4 ph, pl;
#pragma unroll
    for (int r = 0; r < 4; ++r) {
        __bf16 hi = (__bf16)o[r];
        ph.b[r] = hi;
        pl.b[r] = (__bf16)(o[r] - (float)hi);
    }
    *(unsigned long long*)&aH[base] = ph.u;
    *(unsigned long long*)&aL[base] = pl.u;
}

extern "C" void kernel_launch(void* const* d_in, const int* in_sizes, int n_in,
                              void* d_out, int out_size, void* d_ws, size_t ws_size,
                              hipStream_t stream) {
    (void)in_sizes; (void)n_in; (void)out_size; (void)ws_size;
    const float* hs  = (const float*)d_in[0];
    const float* enc = (const float*)d_in[1];
    const float* cs  = (const float*)d_in[2];
    const float* sn  = (const float*)d_in[3];
    const float* wq  = (const float*)d_in[4];
    const float* wk  = (const float*)d_in[5];
    const float* wv  = (const float*)d_in[6];
    const float* wo  = (const float*)d_in[7];
    const float* qnw = (const float*)d_in[8];
    const float* knw = (const float*)d_in[9];
    const int* dm    = (const int*)d_in[10];
    const int* em    = (const int*)d_in[11];
    const int* pos   = (const int*)d_in[12];
    float* out = (float*)d_out;

    char* ws = (char*)d_ws;
    const size_t MB = 1ull << 20;
    __bf16* hs_bf   = (__bf16*)(ws + 0 * MB);    // 8 MB   (dead after gemm_proj)
    __bf16* enc_bf  = (__bf16*)(ws + 8 * MB);    // 8 MB   (dead after gemm_proj)
    __bf16* wqkvTH  = (__bf16*)(ws + 16 * MB);   // 16 MB  (dead after gemm_proj)
    __bf16* wqkvTL  = (__bf16*)(ws + 32 * MB);   // 16 MB  (only v region written)
    __bf16* woTH    = (__bf16*)(ws + 48 * MB);   // 8 MB
    __bf16* woTL    = (__bf16*)(ws + 56 * MB);   // 8 MB
    float*  qf32    = (float*)(ws + 64 * MB);    // 16 MB  (dead after rms_all)
    float*  ksf     = (float*)(ws + 80 * MB);    // 8 MB   (dead after rms_all)
    float*  kcf     = (float*)(ws + 88 * MB);    // 8 MB   (dead after rms_all)
    __bf16* k_bf    = (__bf16*)(ws + 104 * MB);  // 4 MB   [B][KV][S][256]
    __bf16* kc_bf   = (__bf16*)(ws + 108 * MB);  // 4 MB
    __bf16* vtS     = (__bf16*)(ws + 112 * MB);  // 4 MB   [B][KV][256][S]
    __bf16* vtC     = (__bf16*)(ws + 116 * MB);  // 4 MB
    int*    seg     = (int*)(ws + 120 * MB);     // 8 KB
    int*    kinfo   = (int*)(ws + 121 * MB);     // 16 KB
    __bf16* q_bf    = (__bf16*)(ws + 124 * MB);  // 8 MB   [B][S][H][256]
    // reuse of dead regions:
    __bf16* aoutH   = (__bf16*)(ws + 0 * MB);    // 8.39 MB over hs_bf
    __bf16* aoutL   = (__bf16*)(ws + 9 * MB);    // 8.39 MB over enc_bf+wqkvTH head
    float*  accS    = (float*)(ws + 64 * MB);    // 16.78 MB over qf32 (+ksf head)
    float*  accC    = (float*)(ws + 81 * MB);    // 16.78 MB over ksf tail+kcf+gap
    float*  lsS     = (float*)(ws + 98 * MB);    // 64 KB
    float*  lsC     = (float*)(ws + 99 * MB);    // 64 KB

    // 1 launch: tobf16 x2 + tsplit64 x4 + segscan
    prep<<<11266, 256, 0, stream>>>(hs, enc, wq, wk, wv, wo, pos, dm, em,
                                    hs_bf, enc_bf, wqkvTH, wqkvTL, woTH, woTL,
                                    seg, kinfo);

    gemm_proj<<<dim3(48, 16), 256, 0, stream>>>(hs_bf, enc_bf, wqkvTH, wqkvTL,
                                                qf32, ksf, kcf, vtS, vtC);

    rms_all<<<8192, 256, 0, stream>>>(qf32, ksf, kcf, q_bf, k_bf, kc_bf,
                                      qnw, knw, cs, sn);

    attn_part<<<512, 256, 0, stream>>>(q_bf, k_bf, kc_bf, vtS, vtC, seg, kinfo,
                                       accS, accC, lsS, lsC);
    combine<<<4096, 256, 0, stream>>>(accS, accC, lsS, lsC, aoutH, aoutL);

    gemm_out<<<dim3(32, 16), 256, 0, stream>>>(aoutH, aoutL, woTH, woTL, out);
}